// Round 6
// baseline (347.455 us; speedup 1.0000x reference)
//
#include <hip/hip_runtime.h>
#include <stdint.h>

#define N_NODES 50000
#define N_EDGES 800000
#define DIM     128
#define TOT     (N_NODES * DIM)   // 6,400,000
#define SCAN_BLOCKS 196          // 196*256 = 50176 >= 50000
#define GBM 128                  // GEMM block rows
#define BK  32                   // GEMM k-tile
#define OCT 6250                 // nodes per XCD octant (50000/8)
#define BCHUNK 16384             // edges per bucket block (64 iters x 256)

typedef __attribute__((ext_vector_type(8))) unsigned short ushort8_t;

// ---------------- Threefry-2x32 (exact JAX 20-round) ----------------
__host__ __device__ inline void threefry2x32(uint32_t k0, uint32_t k1,
                                             uint32_t x0, uint32_t x1,
                                             uint32_t& o0, uint32_t& o1) {
    uint32_t ks0 = k0, ks1 = k1, ks2 = k0 ^ k1 ^ 0x1BD11BDAu;
    uint32_t v0 = x0 + ks0, v1 = x1 + ks1;
#define TF_R(r) { v0 += v1; v1 = (v1 << (r)) | (v1 >> (32 - (r))); v1 ^= v0; }
    TF_R(13) TF_R(15) TF_R(26) TF_R(6)
    v0 += ks1; v1 += ks2 + 1u;
    TF_R(17) TF_R(29) TF_R(16) TF_R(24)
    v0 += ks2; v1 += ks0 + 2u;
    TF_R(13) TF_R(15) TF_R(26) TF_R(6)
    v0 += ks0; v1 += ks1 + 3u;
    TF_R(17) TF_R(29) TF_R(16) TF_R(24)
    v0 += ks1; v1 += ks2 + 4u;
    TF_R(13) TF_R(15) TF_R(26) TF_R(6)
    v0 += ks2; v1 += ks0 + 5u;
#undef TF_R
    o0 = v0; o1 = v1;
}

__device__ inline float drop_scale(uint32_t kk0, uint32_t kk1, uint32_t i) {
    uint32_t b0, b1;
    threefry2x32(kk0, kk1, 0u, i, b0, b1);
    uint32_t bits = b0 ^ b1;               // partitionable 32-bit path (verified R0)
    return (bits >> 31) ? 0.0f : 2.0f;     // keep iff u < 0.5 iff top bit 0
}

__device__ inline float bf2f(ushort u) {
    return __uint_as_float(((uint32_t)u) << 16);
}

__device__ inline ushort f2bf_rne(float f) {
    uint32_t bits = __float_as_uint(f);
    uint32_t lsb = (bits >> 16) & 1u;
    bits += 0x7fffu + lsb;                 // round-to-nearest-even
    return (ushort)(bits >> 16);
}

// ---------------- degree (A + I), counted at destination ----------------
__global__ void k_degree(const int* __restrict__ dst, uint32_t* __restrict__ deg) {
    int e = blockIdx.x * blockDim.x + threadIdx.x;
    if (e < N_EDGES) atomicAdd(&deg[dst[e]], 1u);
}

__global__ void k_dis(const uint32_t* __restrict__ deg, float* __restrict__ dis) {
    int v = blockIdx.x * blockDim.x + threadIdx.x;
    if (v < N_NODES) dis[v] = 1.0f / sqrtf((float)(deg[v] + 1u));  // +1 self loop
}

// ---------------- CSR build: prefix sum of deg ----------------
__global__ void k_scan1(const uint32_t* __restrict__ deg, uint32_t* __restrict__ row,
                        uint32_t* __restrict__ bsums) {
    __shared__ uint32_t sm[256];
    int i = blockIdx.x * 256 + threadIdx.x;
    uint32_t v = (i < N_NODES) ? deg[i] : 0u;
    sm[threadIdx.x] = v;
    __syncthreads();
    for (int off = 1; off < 256; off <<= 1) {
        uint32_t t = (threadIdx.x >= off) ? sm[threadIdx.x - off] : 0u;
        __syncthreads();
        sm[threadIdx.x] += t;
        __syncthreads();
    }
    if (i < N_NODES) row[i] = sm[threadIdx.x] - v;   // exclusive within block
    if (threadIdx.x == 255) bsums[blockIdx.x] = sm[255];
}

__global__ void k_scan2(uint32_t* __restrict__ bsums) {
    __shared__ uint32_t sm[256];
    int t = threadIdx.x;
    uint32_t v = (t < SCAN_BLOCKS) ? bsums[t] : 0u;
    sm[t] = v;
    __syncthreads();
    for (int off = 1; off < 256; off <<= 1) {
        uint32_t x = (t >= off) ? sm[t - off] : 0u;
        __syncthreads();
        sm[t] += x;
        __syncthreads();
    }
    if (t < SCAN_BLOCKS) bsums[t] = sm[t] - v;       // exclusive
    if (t == 255) bsums[256] = sm[255];               // total at slot 256
}

__global__ void k_scan3(uint32_t* __restrict__ row, uint32_t* __restrict__ cursor,
                        const uint32_t* __restrict__ bsums) {
    int i = blockIdx.x * blockDim.x + threadIdx.x;
    if (i < N_NODES) {
        uint32_t r = row[i] + bsums[i >> 8];
        row[i] = r;
        cursor[i] = r;
    } else if (i == N_NODES) {
        row[i] = bsums[256];
    }
}

// ---------------- CSR bucket fill, XCD-octant swizzled, u16 col ----------------
// Block (g = blockIdx%8, chunk = blockIdx/8): processes edge chunk, keeps only
// edges whose dst lies in octant g. With round-robin blockIdx->XCD mapping, all
// writes into octant g's col region come from one XCD -> no cross-XCD line churn.
__global__ __launch_bounds__(256) void k_bucket(const int* __restrict__ src,
                                                const int* __restrict__ dst,
                                                uint32_t* __restrict__ cursor,
                                                ushort* __restrict__ col16) {
    int g = blockIdx.x & 7;
    int base = (blockIdx.x >> 3) * BCHUNK;
    for (int i = 0; i < BCHUNK / 256; ++i) {
        int e = base + i * 256 + threadIdx.x;
        if (e < N_EDGES) {
            int d = dst[e];
            if (d / OCT == g) {
                int s = src[e];
                uint32_t pos = atomicAdd(&cursor[d], 1u);
                col16[pos] = (ushort)s;
            }
        }
    }
}

// ---------------- H = X @ W, fp32 compute, bf16 scaled, feature-blocked out ----
// Writes Hb[f][v][16] = ((X@W)[v] * dis[v])[f*16..f*16+16) in bf16, f in [0,8).
__global__ __launch_bounds__(256) void k_gemm128(const float* __restrict__ X,
                                                 const float* __restrict__ W,
                                                 const float* __restrict__ dis,
                                                 ushort* __restrict__ Hb) {
    __shared__ float Xs[BK][GBM];
    __shared__ float Ws[BK][DIM];
    int tid = threadIdx.x;
    int m0 = blockIdx.x * GBM;
    int cg = tid & 15;              // cols cg*8 .. cg*8+7
    int rg = tid >> 4;              // rows rg*8 .. rg*8+7 (in tile)
    float acc[8][8] = {};
    const float4* X4 = (const float4*)X;
    const float4* W4 = (const float4*)W;

    for (int kt = 0; kt < DIM; kt += BK) {
        #pragma unroll
        for (int i = 0; i < 4; ++i) {
            int idx = tid + i * 256;             // 0..1023
            int r   = idx >> 3;                  // 0..127
            int kc  = idx & 7;                   // float4 chunk in BK
            int grow = m0 + r;
            int gr = (grow < N_NODES) ? grow : 0;
            float4 xv = X4[gr * 32 + (kt >> 2) + kc];
            Xs[kc * 4 + 0][r] = xv.x;
            Xs[kc * 4 + 1][r] = xv.y;
            Xs[kc * 4 + 2][r] = xv.z;
            Xs[kc * 4 + 3][r] = xv.w;
        }
        #pragma unroll
        for (int i = 0; i < 4; ++i) {
            int idx = tid + i * 256;
            int k   = idx >> 5;
            int c4  = idx & 31;
            *((float4*)&Ws[k][c4 * 4]) = W4[(kt + k) * 32 + c4];
        }
        __syncthreads();

        #pragma unroll 4
        for (int k = 0; k < BK; ++k) {
            float4 xa = *((const float4*)&Xs[k][rg * 8]);
            float4 xb = *((const float4*)&Xs[k][rg * 8 + 4]);
            float4 wa = *((const float4*)&Ws[k][cg * 8]);
            float4 wb = *((const float4*)&Ws[k][cg * 8 + 4]);
            float xr[8] = {xa.x, xa.y, xa.z, xa.w, xb.x, xb.y, xb.z, xb.w};
            float wc[8] = {wa.x, wa.y, wa.z, wa.w, wb.x, wb.y, wb.z, wb.w};
            #pragma unroll
            for (int r = 0; r < 8; ++r)
                #pragma unroll
                for (int c = 0; c < 8; ++c)
                    acc[r][c] += xr[r] * wc[c];
        }
        __syncthreads();
    }

    int f    = cg >> 1;             // feature block (16 feats)
    int half = cg & 1;              // which 8-feat half
    #pragma unroll
    for (int r = 0; r < 8; ++r) {
        int grow = m0 + rg * 8 + r;
        if (grow < N_NODES) {
            float dv = dis[grow];
            ushort* dp = Hb + ((size_t)f * N_NODES + grow) * 16 + half * 8;
            ushort4 s0, s1;
            s0.x = f2bf_rne(acc[r][0] * dv); s0.y = f2bf_rne(acc[r][1] * dv);
            s0.z = f2bf_rne(acc[r][2] * dv); s0.w = f2bf_rne(acc[r][3] * dv);
            s1.x = f2bf_rne(acc[r][4] * dv); s1.y = f2bf_rne(acc[r][5] * dv);
            s1.z = f2bf_rne(acc[r][6] * dv); s1.w = f2bf_rne(acc[r][7] * dv);
            *((ushort4*)dp)     = s0;
            *((ushort4*)(dp+4)) = s1;
        }
    }
}

// ---------------- fused gather, XCD-pinned per feature slice ----------------
// Block (f = blockIdx%8, c = blockIdx/8): nodes c*128.., feature slice f (16).
// Per-XCD resident set: 1.6MB H-slice + 1.6MB col16 + row/dis (~0.6MB) < 4MB L2.
__global__ __launch_bounds__(256) void k_gather(const uint32_t* __restrict__ row,
                                                const ushort* __restrict__ col16,
                                                const float* __restrict__ dis,
                                                const ushort* __restrict__ Hb,
                                                const float* __restrict__ bias,
                                                float* __restrict__ OUT,
                                                uint32_t kk0, uint32_t kk1) {
    int f = blockIdx.x & 7;
    int c = blockIdx.x >> 3;
    int tid = threadIdx.x;
    int v = c * 128 + (tid >> 1);
    int half = tid & 1;
    if (v >= N_NODES) return;
    const ushort* Hf = Hb + (size_t)f * N_NODES * 16;
    const ushort* selfp = Hf + v * 16 + half * 8;
    ushort8_t hv = *((const ushort8_t*)selfp);
    float acc[8];
    #pragma unroll
    for (int j = 0; j < 8; ++j) acc[j] = bf2f(hv[j]);

    uint32_t e0 = row[v], e1 = row[v + 1];
    uint32_t e = e0;
    for (; e + 2 <= e1; e += 2) {
        uint32_t s0 = col16[e], s1 = col16[e + 1];
        ushort8_t h0 = *((const ushort8_t*)(Hf + s0 * 16 + half * 8));
        ushort8_t h1 = *((const ushort8_t*)(Hf + s1 * 16 + half * 8));
        #pragma unroll
        for (int j = 0; j < 8; ++j) acc[j] += bf2f(h0[j]) + bf2f(h1[j]);
    }
    if (e < e1) {
        uint32_t s0 = col16[e];
        ushort8_t h0 = *((const ushort8_t*)(Hf + s0 * 16 + half * 8));
        #pragma unroll
        for (int j = 0; j < 8; ++j) acc[j] += bf2f(h0[j]);
    }

    float dv = dis[v];
    int cbase = f * 16 + half * 8;
    uint32_t ibase = (uint32_t)(v * DIM + cbase);
    float4 o0, o1;
    float* op = (float*)&o0;   // o0,o1 contiguous via separate stores
    #pragma unroll
    for (int j = 0; j < 8; ++j) {
        float z = acc[j] * dv + bias[cbase + j];
        z = (z >= 0.f) ? z : 0.01f * z;
        acc[j] = z * drop_scale(kk0, kk1, ibase + j);
    }
    o0 = make_float4(acc[0], acc[1], acc[2], acc[3]);
    o1 = make_float4(acc[4], acc[5], acc[6], acc[7]);
    float* dp = OUT + (size_t)v * DIM + cbase;
    *((float4*)dp)     = o0;
    *((float4*)(dp+4)) = o1;
    (void)op;
}

// ---------------- classifier GEMM: (N x 128) @ (128 x 2), scaled output ------
__global__ void k_gemm_cls(const float* __restrict__ H, const float* __restrict__ W3,
                           const float* __restrict__ dis, float* __restrict__ O) {
    int v = blockIdx.x * blockDim.x + threadIdx.x;
    if (v >= N_NODES) return;
    const float4* H4 = (const float4*)H;
    float a0 = 0.f, a1 = 0.f;
#pragma unroll 8
    for (int k4 = 0; k4 < 32; ++k4) {
        float4 x = H4[v * 32 + k4];
        const float* w = W3 + k4 * 8;
        a0 += x.x * w[0] + x.y * w[2] + x.z * w[4] + x.w * w[6];
        a1 += x.x * w[1] + x.y * w[3] + x.z * w[5] + x.w * w[7];
    }
    float dv = dis[v];
    O[v * 2 + 0] = a0 * dv;
    O[v * 2 + 1] = a1 * dv;
}

// ---------------- fused layer-3 gather + bias + log_softmax ----------------
__global__ void k_gather3(const uint32_t* __restrict__ row, const ushort* __restrict__ col16,
                          const float* __restrict__ dis,
                          const float* __restrict__ H3s, const float* __restrict__ b3,
                          float* __restrict__ out) {
    int v = blockIdx.x * blockDim.x + threadIdx.x;
    if (v >= N_NODES) return;
    const float2* H2 = (const float2*)H3s;
    float2 h = H2[v];
    float z0 = h.x, z1 = h.y;
    uint32_t e0 = row[v], e1 = row[v + 1];
    uint32_t e = e0;
    for (; e + 2 <= e1; e += 2) {
        float2 ha = H2[col16[e]];
        float2 hb = H2[col16[e + 1]];
        z0 += ha.x + hb.x; z1 += ha.y + hb.y;
    }
    if (e < e1) {
        float2 ha = H2[col16[e]];
        z0 += ha.x; z1 += ha.y;
    }
    float dv = dis[v];
    z0 = z0 * dv + b3[0];
    z1 = z1 * dv + b3[1];
    float m = fmaxf(z0, z1);
    float lse = m + logf(expf(z0 - m) + expf(z1 - m));
    out[v * 2 + 0] = z0 - lse;
    out[v * 2 + 1] = z1 - lse;
}

extern "C" void kernel_launch(void* const* d_in, const int* in_sizes, int n_in,
                              void* d_out, int out_size, void* d_ws, size_t ws_size,
                              hipStream_t stream) {
    const float* x  = (const float*)d_in[0];
    const int*   ei = (const int*)d_in[1];
    const float* W1 = (const float*)d_in[2];
    const float* b1 = (const float*)d_in[3];
    const float* W2 = (const float*)d_in[4];
    const float* b2 = (const float*)d_in[5];
    const float* W3 = (const float*)d_in[6];
    const float* b3 = (const float*)d_in[7];
    float* out = (float*)d_out;

    const int* src = ei;
    const int* dst = ei + N_EDGES;

    // workspace layout (4-byte units)
    uint32_t* wsu = (uint32_t*)d_ws;
    float*    wsf = (float*)d_ws;
    uint32_t* deg    = wsu;                       // [0, 50000)
    float*    dis    = wsf + 50000;               // [50000, 100000)
    uint32_t* row    = wsu + 100000;              // [100000, 150001)
    uint32_t* cursor = wsu + 150016;              // [150016, 200016)
    uint32_t* bsums  = wsu + 200016;              // [200016, 200273) (total at +256)
    ushort*   col16  = (ushort*)(wsu + 200288);   // 800000 u16 = [200288, 600288)
    ushort*   Hb     = (ushort*)(wsu + 600288);   // feat-blocked bf16 H: 6.4M u16
    float*    B      = wsf + 600288 + 3200000;    // fp32 activations, 6.4M floats
    float*    h3s    = wsf + 600288;              // reuse Hb region (100000 floats)

    // dropout keys: threefry-partitionable fold-like split of key(42) (verified R0)
    uint32_t k1a, k1b, k2a, k2b;
    threefry2x32(0u, 42u, 0u, 0u, k1a, k1b);
    threefry2x32(0u, 42u, 0u, 1u, k2a, k2b);

    // ---- graph preprocessing: degree, dis, CSR ----
    hipMemsetAsync(deg, 0, N_NODES * sizeof(uint32_t), stream);
    k_degree<<<(N_EDGES + 255) / 256, 256, 0, stream>>>(dst, deg);
    k_dis<<<(N_NODES + 255) / 256, 256, 0, stream>>>(deg, dis);
    k_scan1<<<SCAN_BLOCKS, 256, 0, stream>>>(deg, row, bsums);
    k_scan2<<<1, 256, 0, stream>>>(bsums);
    k_scan3<<<(N_NODES + 256) / 256, 256, 0, stream>>>(row, cursor, bsums);
    {
        int chunks = (N_EDGES + BCHUNK - 1) / BCHUNK;    // 49
        k_bucket<<<chunks * 8, 256, 0, stream>>>(src, dst, cursor, col16);
    }

    int ggrid = ((N_NODES + 127) / 128) * 8;             // 391*8 = 3128

    // ---- layer 1: x -> Hb(bf16, scaled, feat-blocked) -> B(fp32) ----
    k_gemm128<<<(N_NODES + GBM - 1) / GBM, 256, 0, stream>>>(x, W1, dis, Hb);
    k_gather<<<ggrid, 256, 0, stream>>>(row, col16, dis, Hb, b1, B, k1a, k1b);

    // ---- layer 2: B -> Hb -> B ----
    k_gemm128<<<(N_NODES + GBM - 1) / GBM, 256, 0, stream>>>(B, W2, dis, Hb);
    k_gather<<<ggrid, 256, 0, stream>>>(row, col16, dis, Hb, b2, B, k2a, k2b);

    // ---- layer 3: B -> h3s(pre-scaled) -> out ----
    k_gemm_cls<<<(N_NODES + 255) / 256, 256, 0, stream>>>(B, W3, dis, h3s);
    k_gather3<<<(N_NODES + 255) / 256, 256, 0, stream>>>(row, col16, dis, h3s, b3, out);
}

// Round 7
// 296.038 us; speedup vs baseline: 1.1737x; 1.1737x over previous
//
#include <hip/hip_runtime.h>
#include <stdint.h>

#define N_NODES 50000
#define N_EDGES 800000
#define DIM     128
#define TOT     (N_NODES * DIM)   // 6,400,000
#define GBM 128                  // GEMM block rows
#define BK  32                   // GEMM k-tile
#define NB   196                 // dst buckets: dst>>8, 50000/256 -> 0..195
#define CHUNK 8192               // edges per histogram/scatter block
#define NBLK 98                  // ceil(800000/8192)

typedef __attribute__((ext_vector_type(8))) unsigned short ushort8_t;

// ---------------- Threefry-2x32 (exact JAX 20-round) ----------------
__host__ __device__ inline void threefry2x32(uint32_t k0, uint32_t k1,
                                             uint32_t x0, uint32_t x1,
                                             uint32_t& o0, uint32_t& o1) {
    uint32_t ks0 = k0, ks1 = k1, ks2 = k0 ^ k1 ^ 0x1BD11BDAu;
    uint32_t v0 = x0 + ks0, v1 = x1 + ks1;
#define TF_R(r) { v0 += v1; v1 = (v1 << (r)) | (v1 >> (32 - (r))); v1 ^= v0; }
    TF_R(13) TF_R(15) TF_R(26) TF_R(6)
    v0 += ks1; v1 += ks2 + 1u;
    TF_R(17) TF_R(29) TF_R(16) TF_R(24)
    v0 += ks2; v1 += ks0 + 2u;
    TF_R(13) TF_R(15) TF_R(26) TF_R(6)
    v0 += ks0; v1 += ks1 + 3u;
    TF_R(17) TF_R(29) TF_R(16) TF_R(24)
    v0 += ks1; v1 += ks2 + 4u;
    TF_R(13) TF_R(15) TF_R(26) TF_R(6)
    v0 += ks2; v1 += ks0 + 5u;
#undef TF_R
    o0 = v0; o1 = v1;
}

__device__ inline float drop_scale(uint32_t kk0, uint32_t kk1, uint32_t i) {
    uint32_t b0, b1;
    threefry2x32(kk0, kk1, 0u, i, b0, b1);
    uint32_t bits = b0 ^ b1;               // partitionable 32-bit path (verified R0)
    return (bits >> 31) ? 0.0f : 2.0f;     // keep iff u < 0.5 iff top bit 0
}

__device__ inline float bf2f(ushort u) {
    return __uint_as_float(((uint32_t)u) << 16);
}

__device__ inline ushort f2bf_rne(float f) {
    uint32_t bits = __float_as_uint(f);
    uint32_t lsb = (bits >> 16) & 1u;
    bits += 0x7fffu + lsb;                 // round-to-nearest-even
    return (ushort)(bits >> 16);
}

// ---------------- CSR build phase A: per-block bucket histogram ----------------
__global__ __launch_bounds__(256) void k_hist(const int* __restrict__ dst,
                                              uint32_t* __restrict__ hist) {
    __shared__ uint32_t h[NB];
    int t = threadIdx.x;
    if (t < NB) h[t] = 0u;
    __syncthreads();
    int base = blockIdx.x * CHUNK;
    #pragma unroll
    for (int i = 0; i < CHUNK / 256; ++i) {
        int e = base + i * 256 + t;
        if (e < N_EDGES) atomicAdd(&h[((uint32_t)dst[e]) >> 8], 1u);
    }
    __syncthreads();
    if (t < NB) hist[blockIdx.x * NB + t] = h[t];
}

// ---------------- phase B: offsets. hist[blk][b] -> global write offset --------
__global__ void k_bscan(uint32_t* __restrict__ hist, uint32_t* __restrict__ bb) {
    __shared__ uint32_t cnt[256];
    int t = threadIdx.x;
    uint32_t running = 0;
    if (t < NB) {
        for (int blk = 0; blk < NBLK; ++blk) {
            uint32_t c = hist[blk * NB + t];
            hist[blk * NB + t] = running;    // exclusive within bucket, per block
            running += c;
        }
    }
    cnt[t] = (t < NB) ? running : 0u;        // bucket totals
    __syncthreads();
    for (int off = 1; off < 256; off <<= 1) {
        uint32_t x = (t >= off) ? cnt[t - off] : 0u;
        __syncthreads();
        cnt[t] += x;
        __syncthreads();
    }
    uint32_t incl = cnt[t];
    uint32_t base = incl - ((t < NB) ? running : 0u);   // exclusive bucket base
    if (t < NB) bb[t] = base;
    if (t == NB - 1) bb[NB] = incl;          // total = N_EDGES
    __syncthreads();
    if (t < NB) {
        for (int blk = 0; blk < NBLK; ++blk)
            hist[blk * NB + t] += base;
    }
}

// ---------------- phase C: scatter packed (dlow8,src16), block-contiguous ------
__global__ __launch_bounds__(256) void k_scatter(const int* __restrict__ src,
                                                 const int* __restrict__ dst,
                                                 const uint32_t* __restrict__ hist,
                                                 uint32_t* __restrict__ packed) {
    __shared__ uint32_t cur[NB];
    int t = threadIdx.x;
    int blk = blockIdx.x;
    if (t < NB) cur[t] = hist[blk * NB + t];
    __syncthreads();
    int base = blk * CHUNK;
    #pragma unroll
    for (int i = 0; i < CHUNK / 256; ++i) {
        int e = base + i * 256 + t;
        if (e < N_EDGES) {
            uint32_t d = (uint32_t)dst[e];
            uint32_t s = (uint32_t)src[e];
            uint32_t b = d >> 8;
            uint32_t pos = atomicAdd(&cur[b], 1u);
            packed[pos] = ((d & 255u) << 16) | s;
        }
    }
}

// ---------------- phase D: per-bucket exact CSR + row + dis, line-local --------
__global__ __launch_bounds__(256) void k_fill(const uint32_t* __restrict__ bb,
                                              const uint32_t* __restrict__ packed,
                                              uint32_t* __restrict__ row,
                                              float* __restrict__ dis,
                                              ushort* __restrict__ col16) {
    __shared__ uint32_t sdeg[256];
    __shared__ uint32_t scan[256];
    __shared__ uint32_t cur[256];
    int b = blockIdx.x;
    int t = threadIdx.x;
    uint32_t base = bb[b], n = bb[b + 1] - base;
    sdeg[t] = 0u;
    __syncthreads();
    uint32_t mine[20]; int cnt = 0;
    for (uint32_t i = t; i < n; i += 256) {
        uint32_t u = packed[base + i];
        mine[cnt++] = u;
        atomicAdd(&sdeg[u >> 16], 1u);
    }
    __syncthreads();
    uint32_t myd = sdeg[t];
    scan[t] = myd;
    __syncthreads();
    for (int off = 1; off < 256; off <<= 1) {
        uint32_t x = (t >= off) ? scan[t - off] : 0u;
        __syncthreads();
        scan[t] += x;
        __syncthreads();
    }
    uint32_t excl = scan[t] - myd;
    cur[t] = excl;
    int v = b * 256 + t;
    if (v <= N_NODES) row[v] = base + excl;           // row[50000]=800000 via b=195,t=80
    if (v < N_NODES)  dis[v] = 1.0f / sqrtf((float)(myd + 1u));  // +1 self loop
    __syncthreads();
    for (int j = 0; j < cnt; ++j) {
        uint32_t u = mine[j];
        uint32_t pos = base + atomicAdd(&cur[u >> 16], 1u);
        col16[pos] = (ushort)(u & 0xffffu);
    }
}

// ---------------- H = X @ W, fp32 compute, bf16 scaled, feature-blocked out ----
// Writes Hb[f][v][16] = ((X@W)[v] * dis[v])[f*16..f*16+16) in bf16, f in [0,8).
__global__ __launch_bounds__(256) void k_gemm128(const float* __restrict__ X,
                                                 const float* __restrict__ W,
                                                 const float* __restrict__ dis,
                                                 ushort* __restrict__ Hb) {
    __shared__ float Xs[BK][GBM];
    __shared__ float Ws[BK][DIM];
    int tid = threadIdx.x;
    int m0 = blockIdx.x * GBM;
    int cg = tid & 15;              // cols cg*8 .. cg*8+7
    int rg = tid >> 4;              // rows rg*8 .. rg*8+7 (in tile)
    float acc[8][8] = {};
    const float4* X4 = (const float4*)X;
    const float4* W4 = (const float4*)W;

    for (int kt = 0; kt < DIM; kt += BK) {
        #pragma unroll
        for (int i = 0; i < 4; ++i) {
            int idx = tid + i * 256;             // 0..1023
            int r   = idx >> 3;                  // 0..127
            int kc  = idx & 7;                   // float4 chunk in BK
            int grow = m0 + r;
            int gr = (grow < N_NODES) ? grow : 0;
            float4 xv = X4[gr * 32 + (kt >> 2) + kc];
            Xs[kc * 4 + 0][r] = xv.x;
            Xs[kc * 4 + 1][r] = xv.y;
            Xs[kc * 4 + 2][r] = xv.z;
            Xs[kc * 4 + 3][r] = xv.w;
        }
        #pragma unroll
        for (int i = 0; i < 4; ++i) {
            int idx = tid + i * 256;
            int k   = idx >> 5;
            int c4  = idx & 31;
            *((float4*)&Ws[k][c4 * 4]) = W4[(kt + k) * 32 + c4];
        }
        __syncthreads();

        #pragma unroll 4
        for (int k = 0; k < BK; ++k) {
            float4 xa = *((const float4*)&Xs[k][rg * 8]);
            float4 xb = *((const float4*)&Xs[k][rg * 8 + 4]);
            float4 wa = *((const float4*)&Ws[k][cg * 8]);
            float4 wb = *((const float4*)&Ws[k][cg * 8 + 4]);
            float xr[8] = {xa.x, xa.y, xa.z, xa.w, xb.x, xb.y, xb.z, xb.w};
            float wc[8] = {wa.x, wa.y, wa.z, wa.w, wb.x, wb.y, wb.z, wb.w};
            #pragma unroll
            for (int r = 0; r < 8; ++r)
                #pragma unroll
                for (int c = 0; c < 8; ++c)
                    acc[r][c] += xr[r] * wc[c];
        }
        __syncthreads();
    }

    int f    = cg >> 1;             // feature block (16 feats)
    int half = cg & 1;              // which 8-feat half
    #pragma unroll
    for (int r = 0; r < 8; ++r) {
        int grow = m0 + rg * 8 + r;
        if (grow < N_NODES) {
            float dv = dis[grow];
            ushort* dp = Hb + ((size_t)f * N_NODES + grow) * 16 + half * 8;
            ushort4 s0, s1;
            s0.x = f2bf_rne(acc[r][0] * dv); s0.y = f2bf_rne(acc[r][1] * dv);
            s0.z = f2bf_rne(acc[r][2] * dv); s0.w = f2bf_rne(acc[r][3] * dv);
            s1.x = f2bf_rne(acc[r][4] * dv); s1.y = f2bf_rne(acc[r][5] * dv);
            s1.z = f2bf_rne(acc[r][6] * dv); s1.w = f2bf_rne(acc[r][7] * dv);
            *((ushort4*)dp)     = s0;
            *((ushort4*)(dp+4)) = s1;
        }
    }
}

// ---------------- fused gather, per feature slice ----------------
// Block (f = blockIdx%8, c = blockIdx/8): nodes c*128.., feature slice f (16).
__global__ __launch_bounds__(256) void k_gather(const uint32_t* __restrict__ row,
                                                const ushort* __restrict__ col16,
                                                const float* __restrict__ dis,
                                                const ushort* __restrict__ Hb,
                                                const float* __restrict__ bias,
                                                float* __restrict__ OUT,
                                                uint32_t kk0, uint32_t kk1) {
    int f = blockIdx.x & 7;
    int c = blockIdx.x >> 3;
    int tid = threadIdx.x;
    int v = c * 128 + (tid >> 1);
    int half = tid & 1;
    if (v >= N_NODES) return;
    const ushort* Hf = Hb + (size_t)f * N_NODES * 16;
    const ushort* selfp = Hf + v * 16 + half * 8;
    ushort8_t hv = *((const ushort8_t*)selfp);
    float acc[8];
    #pragma unroll
    for (int j = 0; j < 8; ++j) acc[j] = bf2f(hv[j]);

    uint32_t e0 = row[v], e1 = row[v + 1];
    uint32_t e = e0;
    for (; e + 2 <= e1; e += 2) {
        uint32_t s0 = col16[e], s1 = col16[e + 1];
        ushort8_t h0 = *((const ushort8_t*)(Hf + s0 * 16 + half * 8));
        ushort8_t h1 = *((const ushort8_t*)(Hf + s1 * 16 + half * 8));
        #pragma unroll
        for (int j = 0; j < 8; ++j) acc[j] += bf2f(h0[j]) + bf2f(h1[j]);
    }
    if (e < e1) {
        uint32_t s0 = col16[e];
        ushort8_t h0 = *((const ushort8_t*)(Hf + s0 * 16 + half * 8));
        #pragma unroll
        for (int j = 0; j < 8; ++j) acc[j] += bf2f(h0[j]);
    }

    float dv = dis[v];
    int cbase = f * 16 + half * 8;
    uint32_t ibase = (uint32_t)(v * DIM + cbase);
    #pragma unroll
    for (int j = 0; j < 8; ++j) {
        float z = acc[j] * dv + bias[cbase + j];
        z = (z >= 0.f) ? z : 0.01f * z;
        acc[j] = z * drop_scale(kk0, kk1, ibase + j);
    }
    float4 o0 = make_float4(acc[0], acc[1], acc[2], acc[3]);
    float4 o1 = make_float4(acc[4], acc[5], acc[6], acc[7]);
    float* dp = OUT + (size_t)v * DIM + cbase;
    *((float4*)dp)     = o0;
    *((float4*)(dp+4)) = o1;
}

// ---------------- classifier GEMM: (N x 128) @ (128 x 2), scaled output ------
__global__ void k_gemm_cls(const float* __restrict__ H, const float* __restrict__ W3,
                           const float* __restrict__ dis, float* __restrict__ O) {
    int v = blockIdx.x * blockDim.x + threadIdx.x;
    if (v >= N_NODES) return;
    const float4* H4 = (const float4*)H;
    float a0 = 0.f, a1 = 0.f;
#pragma unroll 8
    for (int k4 = 0; k4 < 32; ++k4) {
        float4 x = H4[v * 32 + k4];
        const float* w = W3 + k4 * 8;
        a0 += x.x * w[0] + x.y * w[2] + x.z * w[4] + x.w * w[6];
        a1 += x.x * w[1] + x.y * w[3] + x.z * w[5] + x.w * w[7];
    }
    float dv = dis[v];
    O[v * 2 + 0] = a0 * dv;
    O[v * 2 + 1] = a1 * dv;
}

// ---------------- fused layer-3 gather + bias + log_softmax ----------------
__global__ void k_gather3(const uint32_t* __restrict__ row, const ushort* __restrict__ col16,
                          const float* __restrict__ dis,
                          const float* __restrict__ H3s, const float* __restrict__ b3,
                          float* __restrict__ out) {
    int v = blockIdx.x * blockDim.x + threadIdx.x;
    if (v >= N_NODES) return;
    const float2* H2 = (const float2*)H3s;
    float2 h = H2[v];
    float z0 = h.x, z1 = h.y;
    uint32_t e0 = row[v], e1 = row[v + 1];
    uint32_t e = e0;
    for (; e + 2 <= e1; e += 2) {
        float2 ha = H2[col16[e]];
        float2 hb = H2[col16[e + 1]];
        z0 += ha.x + hb.x; z1 += ha.y + hb.y;
    }
    if (e < e1) {
        float2 ha = H2[col16[e]];
        z0 += ha.x; z1 += ha.y;
    }
    float dv = dis[v];
    z0 = z0 * dv + b3[0];
    z1 = z1 * dv + b3[1];
    float m = fmaxf(z0, z1);
    float lse = m + logf(expf(z0 - m) + expf(z1 - m));
    out[v * 2 + 0] = z0 - lse;
    out[v * 2 + 1] = z1 - lse;
}

extern "C" void kernel_launch(void* const* d_in, const int* in_sizes, int n_in,
                              void* d_out, int out_size, void* d_ws, size_t ws_size,
                              hipStream_t stream) {
    const float* x  = (const float*)d_in[0];
    const int*   ei = (const int*)d_in[1];
    const float* W1 = (const float*)d_in[2];
    const float* b1 = (const float*)d_in[3];
    const float* W2 = (const float*)d_in[4];
    const float* b2 = (const float*)d_in[5];
    const float* W3 = (const float*)d_in[6];
    const float* b3 = (const float*)d_in[7];
    float* out = (float*)d_out;

    const int* src = ei;
    const int* dst = ei + N_EDGES;

    // workspace layout (4-byte units)
    uint32_t* wsu = (uint32_t*)d_ws;
    float*    wsf = (float*)d_ws;
    uint32_t* hist   = wsu;                       // [0, 19208)  98x196
    uint32_t* bb     = wsu + 19264;               // [19264, 19461) bucket bases (197)
    uint32_t* row    = wsu + 19584;               // [19584, 69585)
    float*    dis    = wsf + 69632;               // [69632, 119632)
    uint32_t* packed = wsu + 119680;              // [119680, 919680)
    ushort*   col16  = (ushort*)(wsu + 919680);   // 800000 u16
    ushort*   Hb     = (ushort*)(wsu + 1319680);  // feat-blocked bf16 H: 6.4M u16
    float*    B      = wsf + 1319680 + 3200000;   // fp32 activations, 6.4M floats
    float*    h3s    = wsf + 1319680;             // reuse Hb region (100000 floats)

    // dropout keys: threefry-partitionable fold-like split of key(42) (verified R0)
    uint32_t k1a, k1b, k2a, k2b;
    threefry2x32(0u, 42u, 0u, 0u, k1a, k1b);
    threefry2x32(0u, 42u, 0u, 1u, k2a, k2b);

    // ---- CSR build: two-level counting sort, block-contiguous writes ----
    k_hist<<<NBLK, 256, 0, stream>>>(dst, hist);
    k_bscan<<<1, 256, 0, stream>>>(hist, bb);
    k_scatter<<<NBLK, 256, 0, stream>>>(src, dst, hist, packed);
    k_fill<<<NB, 256, 0, stream>>>(bb, packed, row, dis, col16);

    int ggrid = ((N_NODES + 127) / 128) * 8;             // 391*8 = 3128

    // ---- layer 1: x -> Hb(bf16, scaled, feat-blocked) -> B(fp32) ----
    k_gemm128<<<(N_NODES + GBM - 1) / GBM, 256, 0, stream>>>(x, W1, dis, Hb);
    k_gather<<<ggrid, 256, 0, stream>>>(row, col16, dis, Hb, b1, B, k1a, k1b);

    // ---- layer 2: B -> Hb -> B ----
    k_gemm128<<<(N_NODES + GBM - 1) / GBM, 256, 0, stream>>>(B, W2, dis, Hb);
    k_gather<<<ggrid, 256, 0, stream>>>(row, col16, dis, Hb, b2, B, k2a, k2b);

    // ---- layer 3: B -> h3s(pre-scaled) -> out ----
    k_gemm_cls<<<(N_NODES + 255) / 256, 256, 0, stream>>>(B, W3, dis, h3s);
    k_gather3<<<(N_NODES + 255) / 256, 256, 0, stream>>>(row, col16, dis, h3s, b3, out);
}